// Round 12
// baseline (135.807 us; speedup 1.0000x reference)
//
#include <hip/hip_runtime.h>
#include <float.h>

#define DIM 64
#define NCODES 512
#define ROWS_PB 64   // 4 waves x 16 rows each
#define NCHUNK 8     // 8 chunks of 64 codes

typedef _Float16 half8 __attribute__((ext_vector_type(8)));
typedef float floatx4 __attribute__((ext_vector_type(4)));

// ws layout (float offsets):
//   et    fp32 [512][64]                      @ 0
//   norms fp32 [512]                          @ 32768
//   ET2   f16  [8 chunk][2 split][4 kt][8 h][16 col][8]  @ 33280  (linear
//         16 KB per chunk = exactly the LDS image global_load_lds stages)
#define WS_NORMS 32768
#define WS_ET2   33280

__global__ __launch_bounds__(256) void vq_prep(const float* __restrict__ emb,
                                               float* __restrict__ ws,
                                               float* __restrict__ loss_slot) {
  __shared__ float T[64][65];
  const int tid = threadIdx.x;
  const int k0 = blockIdx.x * 64;  // block b owns chunk b
  if (blockIdx.x == 0 && tid == 0) loss_slot[0] = 0.0f;
#pragma unroll
  for (int j = 0; j < 16; ++j) {
    const int d = (tid >> 6) + j * 4;
    const int kl = tid & 63;
    T[d][kl] = emb[d * NCODES + k0 + kl];
  }
  __syncthreads();
  float* et = ws;
  float* norms = ws + WS_NORMS;
#pragma unroll
  for (int j = 0; j < 4; ++j) {  // fp32 transposed copy (epilogue gather src)
    const int f = tid + j * 256;
    const int kl = f >> 4;
    const int d4 = (f & 15) << 2;
    float4 q;
    q.x = T[d4 + 0][kl]; q.y = T[d4 + 1][kl];
    q.z = T[d4 + 2][kl]; q.w = T[d4 + 3][kl];
    *(float4*)&et[(size_t)(k0 + kl) * DIM + d4] = q;
  }
  if (tid < 64) {
    float s = 0.0f;
#pragma unroll
    for (int d = 0; d < DIM; ++d) s = fmaf(T[d][tid], T[d][tid], s);
    norms[k0 + tid] = s;
  }
  // f16 hi/lo, chunk-linear layout. Scaled lo: el' = f16((e - f16(e))*2048).
  _Float16* et2 = (_Float16*)(ws + WS_ET2);
#pragma unroll
  for (int i = 0; i < 4; ++i) {
    const int g = i * 256 + tid;        // 0..1023
    const int split = g >> 9;           // 0=hi 1=lo
    const int h = (g >> 6) & 7;         // dim chunk (8 dims)
    const int kl = g & 63;              // code within chunk
    half8 hv;
#pragma unroll
    for (int di = 0; di < 8; ++di) {
      const float v = T[h * 8 + di][kl];
      const _Float16 eh = (_Float16)v;
      const _Float16 el = (_Float16)((v - (float)eh) * 2048.0f);
      hv[di] = split ? el : eh;
    }
    const size_t off = (size_t)blockIdx.x * 8192 + split * 4096 +
                       ((kl >> 4) * 8 + h) * 128 + (kl & 15) * 8;
    *(half8*)(et2 + off) = hv;
  }
}

__device__ __forceinline__ void stage_chunk(const _Float16* __restrict__ et2,
                                            _Float16* dst, int c, int tid) {
  const _Float16* src = et2 + (size_t)c * 8192;
#pragma unroll
  for (int j = 0; j < 4; ++j) {
    const int slot = tid + j * 256;  // dest = wave-uniform + lane*16B (HW rule)
    __builtin_amdgcn_global_load_lds(
        (const __attribute__((address_space(1))) void*)(src + slot * 8),
        (__attribute__((address_space(3))) void*)(dst + slot * 8), 16, 0, 0);
  }
}

// Main: 1024 blocks x 4 waves; wave w owns 16 DISTINCT rows; all 512 codes
// per wave, staged through double-buffered LDS (16 KB chunks via DMA).
// k-loop reads only LDS (ds_read_b128, immediate offsets) -> no L2/L3 stall;
// 4 blocks/CU x 4 waves = 16 waves/CU hide the per-chunk barrier drains.
__global__ __launch_bounds__(256, 4) void vq_main(const float* __restrict__ x,
                                                  const float* __restrict__ ws,
                                                  float* __restrict__ out,
                                                  float* __restrict__ loss,
                                                  float lscale) {
  __shared__ __align__(16) _Float16 sB[2][8192];  // 2 x 16 KB
  __shared__ float snorm[NCODES];
  __shared__ int sfk[ROWS_PB];

  const float* __restrict__ et = ws;
  const float* __restrict__ norms = ws + WS_NORMS;
  const _Float16* __restrict__ et2 = (const _Float16*)(ws + WS_ET2);

  const int tid = threadIdx.x;
  const int lane = tid & 63;
  const int wid = tid >> 6;
  const int col = lane & 15;
  const int quad = lane >> 4;
  const int row0 = blockIdx.x * ROWS_PB;

  stage_chunk(et2, sB[0], 0, tid);  // DMA chunk 0 in flight ASAP
  snorm[tid] = norms[tid];
  snorm[tid + 256] = norms[tid + 256];

  // A-frags (A[m=lane&15][k=quad*8+j], round-7-verified): wave w's rows are
  // row0+16w..+15 (distinct per wave -> no redundant conversion work).
  half8 ah[2], al[2];
  float xn = 0.0f;
#pragma unroll
  for (int ks = 0; ks < 2; ++ks) {
    const float4* xp = (const float4*)x +
                       (size_t)(row0 + wid * 16 + col) * 16 + ks * 8 + quad * 2;
    const float4 f0 = xp[0], f1 = xp[1];
    const float f[8] = {f0.x, f0.y, f0.z, f0.w, f1.x, f1.y, f1.z, f1.w};
#pragma unroll
    for (int j = 0; j < 8; ++j) {
      const float v = f[j];
      xn = fmaf(v, v, xn);
      const _Float16 h = (_Float16)v;
      ah[ks][j] = h;
      al[ks][j] = (_Float16)((v - (float)h) * 2048.0f);
    }
  }
  xn += __shfl_xor(xn, 16);  // full row norm (same value on all quads)
  xn += __shfl_xor(xn, 32);

  float best[4];
  int bk[4];
#pragma unroll
  for (int r = 0; r < 4; ++r) { best[r] = FLT_MAX; bk[r] = 0; }

  __syncthreads();  // chunk 0 staged (barrier drains vmcnt)

  const int lb = quad * 128 + col * 8;  // lane base (halves) within a chunk

#pragma unroll
  for (int c = 0; c < NCHUNK; ++c) {
    if (c + 1 < NCHUNK) stage_chunk(et2, sB[(c + 1) & 1], c + 1, tid);
    const _Float16* B = sB[c & 1];
#pragma unroll
    for (int kt = 0; kt < 4; ++kt) {  // 16-code tiles; all offsets immediate
      const half8 bh0 = *(const half8*)&B[lb + kt * 1024];
      const half8 bh1 = *(const half8*)&B[lb + kt * 1024 + 512];
      const half8 bl0 = *(const half8*)&B[lb + kt * 1024 + 4096];
      const half8 bl1 = *(const half8*)&B[lb + kt * 1024 + 4608];
      const float nk = snorm[c * 64 + kt * 16 + col];
      const int k = c * 64 + kt * 16 + col;
      floatx4 hh = {0.f, 0.f, 0.f, 0.f};
      floatx4 cr0 = {0.f, 0.f, 0.f, 0.f}, cr1 = {0.f, 0.f, 0.f, 0.f};
      hh = __builtin_amdgcn_mfma_f32_16x16x32_f16(ah[0], bh0, hh, 0, 0, 0);
      hh = __builtin_amdgcn_mfma_f32_16x16x32_f16(ah[1], bh1, hh, 0, 0, 0);
      cr0 = __builtin_amdgcn_mfma_f32_16x16x32_f16(al[0], bh0, cr0, 0, 0, 0);
      cr0 = __builtin_amdgcn_mfma_f32_16x16x32_f16(ah[0], bl0, cr0, 0, 0, 0);
      cr1 = __builtin_amdgcn_mfma_f32_16x16x32_f16(al[1], bh1, cr1, 0, 0, 0);
      cr1 = __builtin_amdgcn_mfma_f32_16x16x32_f16(ah[1], bl1, cr1, 0, 0, 0);
#pragma unroll
      for (int r = 0; r < 4; ++r) {
        const float s = fmaf(cr0[r] + cr1[r], 4.8828125e-4f, hh[r]);
        const float dist = fmaf(s, -2.0f, nk);  // ||x||^2 dropped (argmin-inv)
        if (dist < best[r]) { best[r] = dist; bk[r] = k; }  // strict <
      }
    }
    __syncthreads();  // drain c+1 DMA; protect buffer before next overwrite
  }

  // Reduce over 16 col-lanes (xor butterfly); tie -> smaller k (np.argmin)
#pragma unroll
  for (int off = 1; off < 16; off <<= 1) {
#pragma unroll
    for (int r = 0; r < 4; ++r) {
      const float ob = __shfl_xor(best[r], off);
      const int ok = __shfl_xor(bk[r], off);
      if (ob < best[r] || (ob == best[r] && ok < bk[r])) {
        best[r] = ob; bk[r] = ok;
      }
    }
  }

  // Loss: ||x-q||^2 = best + ||x||^2 (xn of row m fetched from col==m lane)
  float ls = 0.0f;
#pragma unroll
  for (int r = 0; r < 4; ++r) {
    const int m = quad * 4 + r;
    const float xnm = __shfl(xn, (lane & 48) | m, 64);
    ls += best[r] + xnm;
  }
  ls = (col == 0) ? ls : 0.0f;
  ls += __shfl_xor(ls, 16);
  ls += __shfl_xor(ls, 32);
  if (lane == 0) atomicAdd(loss, ls * lscale);

  if (col == 0) {
#pragma unroll
    for (int r = 0; r < 4; ++r) sfk[wid * 16 + quad * 4 + r] = bk[r];
  }
  __syncthreads();

  // Epilogue: gather winning fp32 code rows (et is L2-hot), coalesced stores
  {
    float* __restrict__ o = out + (size_t)row0 * DIM;
#pragma unroll
    for (int j = 0; j < 4; ++j) {
      const int f = tid + j * 256;   // 0..1023
      const int r = f >> 4;          // row 0..63
      const int c4 = (f & 15) << 2;  // col 0..60
      const int k = sfk[r];
      *(float4*)&o[(size_t)r * DIM + c4] = *(const float4*)&et[(size_t)k * DIM + c4];
    }
  }
}

extern "C" void kernel_launch(void* const* d_in, const int* in_sizes, int n_in,
                              void* d_out, int out_size, void* d_ws, size_t ws_size,
                              hipStream_t stream) {
  const float* x = (const float*)d_in[0];    // (64,32,32,64) fp32
  const float* emb = (const float*)d_in[1];  // (64,512) fp32
  float* out = (float*)d_out;                // out (4194304) + loss (1)

  const int nrows = in_sizes[0] / DIM;       // 65536
  float* ws = (float*)d_ws;                  // 264 KB used
  float* loss = out + (out_size - 1);

  vq_prep<<<NCODES / 64, 256, 0, stream>>>(emb, ws, loss);

  const float lscale = 1.25f / (float)(nrows * DIM);  // (1+beta)/numel
  vq_main<<<nrows / ROWS_PB, 256, 0, stream>>>(x, ws, out, loss, lscale);
}